// Round 3
// baseline (864.870 us; speedup 1.0000x reference)
//
#include <hip/hip_runtime.h>

#define CIN  32
#define COUT 32

// One kernel per rulebook offset k, launched sequentially on the stream.
// Within one k the input->output map is injective (pure spatial translation,
// unique input coords), so no two pairs of the same k share an output row:
// plain read-modify-write, NO atomics. Cross-k ordering comes from the stream.
// Half-wave (32 lanes) per pair; lane = output channel; W[k] column in VGPRs.
__global__ __launch_bounds__(256, 4)
void spconv_k(const float* __restrict__ feat,
              const float* __restrict__ wk,     // this k's 32x32 weight
              const int*   __restrict__ gk,     // this k's gather row
              const int*   __restrict__ sk,     // this k's scatter row
              float*       __restrict__ out,
              int npair, int M)
{
    const int lane = threadIdx.x & 31;   // output channel
    const int sub  = threadIdx.x >> 5;   // half-wave slot within block
    const int slots = (blockDim.x >> 5) * gridDim.x;

    // per-lane weight column: w[i] = W[k][i][lane]
    float w[CIN];
#pragma unroll
    for (int i = 0; i < CIN; ++i) w[i] = wk[i * COUT + lane];

    for (int p = blockIdx.x * (blockDim.x >> 5) + sub; p < npair; p += slots) {
        const int s = sk[p];
        if (s >= M) continue;            // padded / dummy pair (tail)
        const int g = gk[p];

        float* o = out + (size_t)s * COUT + lane;
        float old = *o;                  // issue RMW read early (HBM miss)

        const float4* fr = (const float4*)(feat + (size_t)g * CIN);
        float acc = 0.f;
#pragma unroll
        for (int c = 0; c < 8; ++c) {
            float4 f4 = fr[c];           // uniform address -> L1 broadcast
            acc = fmaf(f4.x, w[4 * c + 0], acc);
            acc = fmaf(f4.y, w[4 * c + 1], acc);
            acc = fmaf(f4.z, w[4 * c + 2], acc);
            acc = fmaf(f4.w, w[4 * c + 3], acc);
        }
        *o = old + acc;                  // plain store, collision-free within k
    }
}

extern "C" void kernel_launch(void* const* d_in, const int* in_sizes, int n_in,
                              void* d_out, int out_size, void* d_ws, size_t ws_size,
                              hipStream_t stream)
{
    const float* feat    = (const float*)d_in[0];
    const float* weight  = (const float*)d_in[1];
    const int*   gather  = (const int*)d_in[2];
    const int*   scatter = (const int*)d_in[3];
    float*       out     = (float*)d_out;

    const int K     = in_sizes[1] / (CIN * COUT);   // 27
    const int npair = in_sizes[2] / K;              // 150000
    const int M     = out_size / COUT;              // num_out

    // Output must be zeroed every call (harness poisons once, never restores).
    hipMemsetAsync(d_out, 0, (size_t)out_size * sizeof(float), stream);

    // 2048 blocks x 8 half-waves = 16384 slots; ~9 pairs per slot.
    for (int k = 0; k < K; ++k) {
        spconv_k<<<2048, 256, 0, stream>>>(feat,
                                           weight + (size_t)k * CIN * COUT,
                                           gather + (size_t)k * npair,
                                           scatter + (size_t)k * npair,
                                           out, npair, M);
    }
}